// Round 1
// baseline (508.190 us; speedup 1.0000x reference)
//
#include <hip/hip_runtime.h>
#include <math.h>

// Problem constants (fixed by the reference: B=16, S=2048, D=512).
constexpr int Bc = 16;
constexpr int Sc = 2048;
constexpr int Dc = 512;
constexpr int NA = Sc - 3;      // 2045 anchors: seq positions 1 .. S-3
constexpr float MAXD = 32.0f;   // MAX_DIST

// Numerically stable softplus: log(1+e^x) = max(x,0) + log1p(e^{-|x|}).
// Distances here are ~545, so the naive form overflows.
__device__ __forceinline__ float softplus_stable(float x) {
    return fmaxf(x, 0.0f) + log1pf(__expf(-fabsf(x)));
}

// One wave (64 lanes) per (b, anchor). Lane l holds 8 consecutive floats of
// the anchor row (2 x float4, coalesced 16B/lane). All 6 targets' per-lane
// partials are computed in one unrolled loop so the 12 float4 loads can be
// in flight together, then 6 interleaved butterfly shuffle-reductions.
__global__ __launch_bounds__(256) void signcl_kernel(
    const float* __restrict__ x,
    const int* __restrict__ pos_idx,
    const int* __restrict__ neg_idx,
    float* __restrict__ out)
{
    const int gtid = blockIdx.x * blockDim.x + threadIdx.x;
    const int wave = gtid >> 6;
    const int lane = threadIdx.x & 63;
    if (wave >= Bc * NA) return;
    const int b = wave / NA;
    const int a = wave - b * NA;         // anchor index 0..NA-1, seq pos a+1

    const float* base = x + (size_t)b * Sc * Dc;
    const float4* av = reinterpret_cast<const float4*>(base + (size_t)(a + 1) * Dc);
    const float4 a0 = av[2 * lane];
    const float4 a1 = av[2 * lane + 1];

    int idx[6];
    idx[0] = pos_idx[2 * a];
    idx[1] = pos_idx[2 * a + 1];
#pragma unroll
    for (int t = 0; t < 4; ++t) idx[2 + t] = neg_idx[4 * a + t];

    float part[6];
#pragma unroll
    for (int t = 0; t < 6; ++t) {
        const float4* tv = reinterpret_cast<const float4*>(base + (size_t)idx[t] * Dc);
        const float4 t0 = tv[2 * lane];
        const float4 t1 = tv[2 * lane + 1];
        part[t] = fabsf(a0.x - t0.x) + fabsf(a0.y - t0.y)
                + fabsf(a0.z - t0.z) + fabsf(a0.w - t0.w)
                + fabsf(a1.x - t1.x) + fabsf(a1.y - t1.y)
                + fabsf(a1.z - t1.z) + fabsf(a1.w - t1.w);
    }

    // 64-lane butterfly reduction, 6 chains interleaved.
#pragma unroll
    for (int off = 32; off >= 1; off >>= 1) {
#pragma unroll
        for (int t = 0; t < 6; ++t)
            part[t] += __shfl_down(part[t], off, 64);
    }

    if (lane == 0) {
        // pos_loss: mean over (B, 2) then summed; neg_loss: mean over (B, 4);
        // final division by B*(S-4). Fold all scaling into per-term weights.
        const float wpos = 1.0f / ((float)Bc * 2.0f * (float)Bc * (float)(Sc - 4));
        const float wneg = 1.0f / ((float)Bc * 4.0f * (float)Bc * (float)(Sc - 4));
        float v = wpos * (softplus_stable(part[0] - MAXD) +
                          softplus_stable(part[1] - MAXD))
                + wneg * (softplus_stable(MAXD - part[2]) +
                          softplus_stable(MAXD - part[3]) +
                          softplus_stable(MAXD - part[4]) +
                          softplus_stable(MAXD - part[5]));
        atomicAdd(out, v);
    }
}

extern "C" void kernel_launch(void* const* d_in, const int* in_sizes, int n_in,
                              void* d_out, int out_size, void* d_ws, size_t ws_size,
                              hipStream_t stream) {
    const float* x   = (const float*)d_in[0];   // (B, S, D) float32
    const int*   pos = (const int*)d_in[1];     // (NA, 2) int32
    const int*   neg = (const int*)d_in[2];     // (NA, 4) int32
    float* out = (float*)d_out;                 // scalar float32

    // d_out is poisoned (0xAA) before every timed launch — zero it on-stream.
    hipMemsetAsync(out, 0, sizeof(float) * (size_t)out_size, stream);

    const int total_waves = Bc * NA;            // 32720
    const int threads = 256;                    // 4 waves/block
    const int blocks = (total_waves + 3) / 4;   // 8180
    signcl_kernel<<<blocks, threads, 0, stream>>>(x, pos, neg, out);
}

// Round 2
// 134.257 us; speedup vs baseline: 3.7852x; 3.7852x over previous
//
#include <hip/hip_runtime.h>
#include <math.h>

// Problem constants (fixed by the reference: B=16, S=2048, D=512).
constexpr int Bc = 16;
constexpr int Sc = 2048;
constexpr int Dc = 512;
constexpr int NA = Sc - 3;      // 2045 anchors: seq positions 1 .. S-3
constexpr float MAXD = 32.0f;   // MAX_DIST
constexpr int WAVES_PER_BLOCK = 4;
constexpr int NBLOCKS = (Bc * NA) / WAVES_PER_BLOCK;  // 32720/4 = 8180 exact

// Numerically stable softplus: log(1+e^x) = max(x,0) + log1p(e^{-|x|}).
// Distances here are ~545, so the naive form overflows.
__device__ __forceinline__ float softplus_stable(float x) {
    return fmaxf(x, 0.0f) + log1pf(__expf(-fabsf(x)));
}

// One wave (64 lanes) per (b, anchor). Lane l holds 8 consecutive floats of
// the anchor row (2 x float4, coalesced 16B/lane). All 6 targets' per-lane
// partials are computed in one unrolled loop so the 12 float4 loads can be
// in flight together, then 6 interleaved butterfly shuffle-reductions.
// Block partials go to d_ws — NO single-address atomics (R1: 32720 atomicAdds
// to one address serialized at ~13ns each = the whole 428us).
__global__ __launch_bounds__(256) void signcl_kernel(
    const float* __restrict__ x,
    const int* __restrict__ pos_idx,
    const int* __restrict__ neg_idx,
    float* __restrict__ partials)
{
    const int gtid = blockIdx.x * blockDim.x + threadIdx.x;
    const int wave = gtid >> 6;
    const int lane = threadIdx.x & 63;
    const int b = wave / NA;
    const int a = wave - b * NA;         // anchor index 0..NA-1, seq pos a+1

    const float* base = x + (size_t)b * Sc * Dc;
    const float4* av = reinterpret_cast<const float4*>(base + (size_t)(a + 1) * Dc);
    const float4 a0 = av[2 * lane];
    const float4 a1 = av[2 * lane + 1];

    int idx[6];
    idx[0] = pos_idx[2 * a];
    idx[1] = pos_idx[2 * a + 1];
#pragma unroll
    for (int t = 0; t < 4; ++t) idx[2 + t] = neg_idx[4 * a + t];

    float part[6];
#pragma unroll
    for (int t = 0; t < 6; ++t) {
        const float4* tv = reinterpret_cast<const float4*>(base + (size_t)idx[t] * Dc);
        const float4 t0 = tv[2 * lane];
        const float4 t1 = tv[2 * lane + 1];
        part[t] = fabsf(a0.x - t0.x) + fabsf(a0.y - t0.y)
                + fabsf(a0.z - t0.z) + fabsf(a0.w - t0.w)
                + fabsf(a1.x - t1.x) + fabsf(a1.y - t1.y)
                + fabsf(a1.z - t1.z) + fabsf(a1.w - t1.w);
    }

    // 64-lane butterfly reduction, 6 chains interleaved.
#pragma unroll
    for (int off = 32; off >= 1; off >>= 1) {
#pragma unroll
        for (int t = 0; t < 6; ++t)
            part[t] += __shfl_down(part[t], off, 64);
    }

    __shared__ float wsum[WAVES_PER_BLOCK];
    if (lane == 0) {
        // pos_loss: mean over (B, 2) then summed; neg_loss: mean over (B, 4);
        // final division by B*(S-4). Fold all scaling into per-term weights.
        const float wpos = 1.0f / ((float)Bc * 2.0f * (float)Bc * (float)(Sc - 4));
        const float wneg = 1.0f / ((float)Bc * 4.0f * (float)Bc * (float)(Sc - 4));
        float v = wpos * (softplus_stable(part[0] - MAXD) +
                          softplus_stable(part[1] - MAXD))
                + wneg * (softplus_stable(MAXD - part[2]) +
                          softplus_stable(MAXD - part[3]) +
                          softplus_stable(MAXD - part[4]) +
                          softplus_stable(MAXD - part[5]));
        wsum[threadIdx.x >> 6] = v;
    }
    __syncthreads();
    if (threadIdx.x == 0) {
        partials[blockIdx.x] = wsum[0] + wsum[1] + wsum[2] + wsum[3];
    }
}

// Single-block final reduction of the 8180 block partials.
__global__ __launch_bounds__(256) void signcl_finalize(
    const float* __restrict__ partials, float* __restrict__ out)
{
    const int tid = threadIdx.x;
    float acc = 0.0f;
    for (int i = tid; i < NBLOCKS; i += 256) acc += partials[i];

    __shared__ float smem[4];
#pragma unroll
    for (int off = 32; off >= 1; off >>= 1) acc += __shfl_down(acc, off, 64);
    if ((tid & 63) == 0) smem[tid >> 6] = acc;
    __syncthreads();
    if (tid == 0) out[0] = smem[0] + smem[1] + smem[2] + smem[3];
}

extern "C" void kernel_launch(void* const* d_in, const int* in_sizes, int n_in,
                              void* d_out, int out_size, void* d_ws, size_t ws_size,
                              hipStream_t stream) {
    const float* x   = (const float*)d_in[0];   // (B, S, D) float32
    const int*   pos = (const int*)d_in[1];     // (NA, 2) int32
    const int*   neg = (const int*)d_in[2];     // (NA, 4) int32
    float* out = (float*)d_out;                 // scalar float32
    float* partials = (float*)d_ws;             // 8180 floats = 32.7 KB

    signcl_kernel<<<NBLOCKS, 256, 0, stream>>>(x, pos, neg, partials);
    signcl_finalize<<<1, 256, 0, stream>>>(partials, out);
}

// Round 3
// 130.750 us; speedup vs baseline: 3.8867x; 1.0268x over previous
//
#include <hip/hip_runtime.h>
#include <math.h>

// Problem constants (fixed by the reference: B=16, S=2048, D=512).
constexpr int Bc = 16;
constexpr int Sc = 2048;
constexpr int Dc = 512;
constexpr int NA = Sc - 3;        // 2045 anchors: seq positions 1 .. S-3
constexpr float MAXD = 32.0f;     // MAX_DIST

constexpr int NBLK = 2048;                     // persistent grid: 8 XCDs x 256
constexpr int WPB = 4;                         // waves per 256-thread block
constexpr int WAVES_PER_XCD = (NBLK / 8) * WPB;  // 1024
constexpr int ITEMS_PER_XCD = 2 * NA;          // 4090: batches j and j+8 on XCD j

// Numerically stable softplus: log(1+e^x) = max(x,0) + log1p(e^{-|x|}).
// Distances here are ~545, so the naive form overflows.
__device__ __forceinline__ float softplus_stable(float x) {
    return fmaxf(x, 0.0f) + log1pf(__expf(-fabsf(x)));
}

// One XOR-butterfly step over all 6 chains: ds_swizzle BitMode
// offset = (xor_mask<<10) | 0x1F — a single DS instr + add per chain,
// vs ~4 instrs for __shfl_down. Works within 32-lane groups.
#define SWSTEP(arr, MASKOFF)                                                   \
    _Pragma("unroll")                                                          \
    for (int _t = 0; _t < 6; ++_t) {                                           \
        int _tmp = __builtin_amdgcn_ds_swizzle(__float_as_int(arr[_t]),        \
                                               MASKOFF);                       \
        arr[_t] += __int_as_float(_tmp);                                       \
    }

// Persistent kernel. blockIdx&7 selects the XCD (dispatch is round-robin by
// heuristic); XCD j owns batches j and j+8, so each XCD's L2 mostly holds its
// own 2 x 4MB batch slices instead of all 16 (R2: FETCH was 2x unique input
// from cross-XCD replication). Waves grid-stride over ~4 (b,anchor) items,
// amortizing prologue. Lane l holds 8 floats of the anchor row (2 x float4).
__global__ __launch_bounds__(256) void signcl_kernel(
    const float* __restrict__ x,
    const int* __restrict__ pos_idx,
    const int* __restrict__ neg_idx,
    float* __restrict__ partials)
{
    const int lane = threadIdx.x & 63;
    const int wib  = threadIdx.x >> 6;        // wave within block
    const int xcd  = blockIdx.x & 7;
    const int sub  = blockIdx.x >> 3;         // 0..255
    const int wid  = sub * WPB + wib;         // wave id within XCD, 0..1023

    // pos_loss: mean over (B,2) then summed over anchors; neg: mean over
    // (B,4); final /(B*(S-4)). Fold everything into per-term weights.
    const float wpos = 1.0f / ((float)Bc * 2.0f * (float)Bc * (float)(Sc - 4));
    const float wneg = 1.0f / ((float)Bc * 4.0f * (float)Bc * (float)(Sc - 4));

    float acc = 0.0f;
    for (int item = wid; item < ITEMS_PER_XCD; item += WAVES_PER_XCD) {
        const int bb = item / NA;             // 0 or 1
        const int a  = item - bb * NA;        // anchor 0..NA-1, seq pos a+1
        const int b  = xcd + 8 * bb;

        const float* base = x + (size_t)b * Sc * Dc;
        const float4* av =
            reinterpret_cast<const float4*>(base + (size_t)(a + 1) * Dc);
        const float4 a0 = av[2 * lane];
        const float4 a1 = av[2 * lane + 1];

        int idx[6];
        idx[0] = pos_idx[2 * a];
        idx[1] = pos_idx[2 * a + 1];
#pragma unroll
        for (int t = 0; t < 4; ++t) idx[2 + t] = neg_idx[4 * a + t];

        float part[6];
#pragma unroll
        for (int t = 0; t < 6; ++t) {
            const float4* tv =
                reinterpret_cast<const float4*>(base + (size_t)idx[t] * Dc);
            const float4 t0 = tv[2 * lane];
            const float4 t1 = tv[2 * lane + 1];
            part[t] = fabsf(a0.x - t0.x) + fabsf(a0.y - t0.y)
                    + fabsf(a0.z - t0.z) + fabsf(a0.w - t0.w)
                    + fabsf(a1.x - t1.x) + fabsf(a1.y - t1.y)
                    + fabsf(a1.z - t1.z) + fabsf(a1.w - t1.w);
        }

        // Butterfly within each 32-lane group (5 steps), then combine the two
        // half-wave sums with scalar readlanes (results are wave-uniform).
        SWSTEP(part, 0x041F)   // xor 1
        SWSTEP(part, 0x081F)   // xor 2
        SWSTEP(part, 0x101F)   // xor 4
        SWSTEP(part, 0x201F)   // xor 8
        SWSTEP(part, 0x401F)   // xor 16

        float d[6];
#pragma unroll
        for (int t = 0; t < 6; ++t) {
            int lo = __builtin_amdgcn_readlane(__float_as_int(part[t]), 0);
            int hi = __builtin_amdgcn_readlane(__float_as_int(part[t]), 32);
            d[t] = __int_as_float(lo) + __int_as_float(hi);
        }

        acc += wpos * (softplus_stable(d[0] - MAXD) +
                       softplus_stable(d[1] - MAXD))
             + wneg * (softplus_stable(MAXD - d[2]) +
                       softplus_stable(MAXD - d[3]) +
                       softplus_stable(MAXD - d[4]) +
                       softplus_stable(MAXD - d[5]));
    }

    // acc is wave-uniform; reduce 4 waves through LDS, one write per block.
    __shared__ float wsum[WPB];
    if (lane == 0) wsum[wib] = acc;
    __syncthreads();
    if (threadIdx.x == 0)
        partials[blockIdx.x] = wsum[0] + wsum[1] + wsum[2] + wsum[3];
}

// Single-block final reduction of the 2048 contiguous block partials (~2 us).
__global__ __launch_bounds__(256) void signcl_finalize(
    const float* __restrict__ partials, float* __restrict__ out)
{
    const int tid = threadIdx.x;
    float acc = 0.0f;
#pragma unroll
    for (int i = 0; i < NBLK / 256; ++i) acc += partials[i * 256 + tid];

    __shared__ float smem[4];
#pragma unroll
    for (int off = 32; off >= 1; off >>= 1) acc += __shfl_down(acc, off, 64);
    if ((tid & 63) == 0) smem[tid >> 6] = acc;
    __syncthreads();
    if (tid == 0) out[0] = smem[0] + smem[1] + smem[2] + smem[3];
}

extern "C" void kernel_launch(void* const* d_in, const int* in_sizes, int n_in,
                              void* d_out, int out_size, void* d_ws, size_t ws_size,
                              hipStream_t stream) {
    const float* x   = (const float*)d_in[0];   // (B, S, D) float32
    const int*   pos = (const int*)d_in[1];     // (NA, 2) int32
    const int*   neg = (const int*)d_in[2];     // (NA, 4) int32
    float* out = (float*)d_out;                 // scalar float32
    float* partials = (float*)d_ws;             // 2048 floats = 8 KB

    signcl_kernel<<<NBLK, 256, 0, stream>>>(x, pos, neg, partials);
    signcl_finalize<<<1, 256, 0, stream>>>(partials, out);
}

// Round 4
// 110.366 us; speedup vs baseline: 4.6046x; 1.1847x over previous
//
#include <hip/hip_runtime.h>
#include <math.h>

// Problem constants (fixed by the reference: B=16, S=2048, D=512).
constexpr int Bc = 16;
constexpr int Sc = 2048;
constexpr int Dc = 512;
constexpr int NA = Sc - 3;            // 2045 anchors: seq positions 1 .. S-3
constexpr float MAXD = 32.0f;         // MAX_DIST

constexpr int ITEMS_PER_XCD = 2 * NA;                 // 4090 (batches j, j+8)
constexpr int BLK_PER_XCD = (ITEMS_PER_XCD + 3) / 4;  // 1023 blocks of 4 waves
constexpr int NBLK = 8 * BLK_PER_XCD;                 // 8184

// Fast numerically-stable softplus: max(x,0) + log(1 + e^{-|x|}).
// __expf/__logf -> v_exp_f32/v_log_f32 (~6 VALU) vs libm log1pf (~35 VALU).
// Distances here are ~545 so both branches saturate; f32 ulp error is fine
// against the 0.685 threshold.
__device__ __forceinline__ float softplus_fast(float x) {
    return fmaxf(x, 0.0f) + __logf(1.0f + __expf(-fabsf(x)));
}

// One wave64 sum-reduction step as a single v_add_f32 with DPP (no DS, no
// lgkmcnt): masked-out lanes get old=0 from update_dpp and add 0.
template <int CTRL, int RMASK>
__device__ __forceinline__ float dpp_add(float x) {
    int y = __builtin_amdgcn_update_dpp(0, __float_as_int(x), CTRL, RMASK, 0xF, true);
    return x + __int_as_float(y);
}

// Full wave64 reduction over 6 independent chains, interleaved for ILP.
// After this, lanes 48..63 hold the full 64-lane sum of each chain.
__device__ __forceinline__ void wave_reduce6(float p[6]) {
#pragma unroll
    for (int t = 0; t < 6; ++t) p[t] = dpp_add<0xB1, 0xF>(p[t]);  // quad_perm xor1
#pragma unroll
    for (int t = 0; t < 6; ++t) p[t] = dpp_add<0x4E, 0xF>(p[t]);  // quad_perm xor2
#pragma unroll
    for (int t = 0; t < 6; ++t) p[t] = dpp_add<0x141, 0xF>(p[t]); // row_half_mirror
#pragma unroll
    for (int t = 0; t < 6; ++t) p[t] = dpp_add<0x140, 0xF>(p[t]); // row_mirror
#pragma unroll
    for (int t = 0; t < 6; ++t) p[t] = dpp_add<0x142, 0xA>(p[t]); // row_bcast15
#pragma unroll
    for (int t = 0; t < 6; ++t) p[t] = dpp_add<0x143, 0xC>(p[t]); // row_bcast31
}

// One wave per (b, anchor) item — full TLP (R3's 4-items/wave persistent loop
// serialized the per-item latency chains and regressed). XCD-pinned: blockIdx&7
// selects the XCD; XCD j owns batches j and j+8 (R3: FETCH 134->72 MB).
__global__ __launch_bounds__(256) void signcl_kernel(
    const float* __restrict__ x,
    const int* __restrict__ pos_idx,
    const int* __restrict__ neg_idx,
    float* __restrict__ partials)
{
    const int lane = threadIdx.x & 63;
    const int wib  = threadIdx.x >> 6;          // wave within block
    const int xcd  = blockIdx.x & 7;
    const int sub  = blockIdx.x >> 3;           // 0..BLK_PER_XCD-1
    const int item = sub * 4 + wib;             // item within this XCD
    const bool valid = item < ITEMS_PER_XCD;

    float acc = 0.0f;                           // meaningful in lane 63 only
    if (valid) {
        const int bb = (item >= NA) ? 1 : 0;
        const int a  = item - bb * NA;          // anchor 0..NA-1, seq pos a+1
        const int b  = xcd + 8 * bb;

        const float* base = x + (size_t)b * Sc * Dc;
        const float4* av =
            reinterpret_cast<const float4*>(base + (size_t)(a + 1) * Dc);
        const float4 a0 = av[2 * lane];
        const float4 a1 = av[2 * lane + 1];

        // Gather indices are wave-uniform: force them scalar so target
        // address math lands in SALU, not per-lane VALU.
        int idx[6];
        idx[0] = __builtin_amdgcn_readfirstlane(pos_idx[2 * a]);
        idx[1] = __builtin_amdgcn_readfirstlane(pos_idx[2 * a + 1]);
#pragma unroll
        for (int t = 0; t < 4; ++t)
            idx[2 + t] = __builtin_amdgcn_readfirstlane(neg_idx[4 * a + t]);

        float part[6];
#pragma unroll
        for (int t = 0; t < 6; ++t) {
            const float4* tv =
                reinterpret_cast<const float4*>(base + (size_t)idx[t] * Dc);
            const float4 t0 = tv[2 * lane];
            const float4 t1 = tv[2 * lane + 1];
            part[t] = fabsf(a0.x - t0.x) + fabsf(a0.y - t0.y)
                    + fabsf(a0.z - t0.z) + fabsf(a0.w - t0.w)
                    + fabsf(a1.x - t1.x) + fabsf(a1.y - t1.y)
                    + fabsf(a1.z - t1.z) + fabsf(a1.w - t1.w);
        }

        wave_reduce6(part);                     // totals land in lanes 48..63

        if (lane == 63) {
            // pos: mean over (B,2) summed over anchors; neg: mean over (B,4);
            // final /(B*(S-4)) — folded into per-term weights.
            const float wpos =
                1.0f / ((float)Bc * 2.0f * (float)Bc * (float)(Sc - 4));
            const float wneg =
                1.0f / ((float)Bc * 4.0f * (float)Bc * (float)(Sc - 4));
            acc = wpos * (softplus_fast(part[0] - MAXD) +
                          softplus_fast(part[1] - MAXD))
                + wneg * (softplus_fast(MAXD - part[2]) +
                          softplus_fast(MAXD - part[3]) +
                          softplus_fast(MAXD - part[4]) +
                          softplus_fast(MAXD - part[5]));
        }
    }

    __shared__ float wsum[4];
    if (lane == 63) wsum[wib] = acc;            // invalid waves write 0
    __syncthreads();
    if (threadIdx.x == 0)
        partials[blockIdx.x] = wsum[0] + wsum[1] + wsum[2] + wsum[3];
}

// Final reduction of the 8184 contiguous block partials. 1024 threads so the
// 8 loads/thread are independent and pipeline behind one latency.
__global__ __launch_bounds__(1024) void signcl_finalize(
    const float* __restrict__ partials, float* __restrict__ out)
{
    const int tid = threadIdx.x;
    float acc = 0.0f;
#pragma unroll
    for (int k = 0; k < 8; ++k) {
        int i = tid + k * 1024;
        if (i < NBLK) acc += partials[i];
    }

    // wave64 DPP reduce, then 16 wave-partials through LDS.
    float p[6] = {acc, 0, 0, 0, 0, 0};
    wave_reduce6(p);
    __shared__ float smem[16];
    if ((tid & 63) == 63) smem[tid >> 6] = p[0];
    __syncthreads();
    if (tid == 0) {
        float s = 0.0f;
#pragma unroll
        for (int i = 0; i < 16; ++i) s += smem[i];
        out[0] = s;
    }
}

extern "C" void kernel_launch(void* const* d_in, const int* in_sizes, int n_in,
                              void* d_out, int out_size, void* d_ws, size_t ws_size,
                              hipStream_t stream) {
    const float* x   = (const float*)d_in[0];   // (B, S, D) float32
    const int*   pos = (const int*)d_in[1];     // (NA, 2) int32
    const int*   neg = (const int*)d_in[2];     // (NA, 4) int32
    float* out = (float*)d_out;                 // scalar float32
    float* partials = (float*)d_ws;             // 8184 floats = 32.7 KB

    signcl_kernel<<<NBLK, 256, 0, stream>>>(x, pos, neg, partials);
    signcl_finalize<<<1, 1024, 0, stream>>>(partials, out);
}